// Round 4
// baseline (370.750 us; speedup 1.0000x reference)
//
#include <hip/hip_runtime.h>
#include <math.h>

#define NEG_SLOPE 0.2f

// fp32 -> bf16 with round-to-nearest-even (no NaN handling needed here)
__device__ __forceinline__ unsigned f2bf(float f) {
    unsigned u = __float_as_uint(f);
    return (u + 0x7fffu + ((u >> 16) & 1u)) >> 16;
}

// ============================================================
// CSR build: count+rank -> scan (3 kernels) -> atomic-free fill
// ============================================================

__global__ __launch_bounds__(256) void count_rank_k(
    const int* __restrict__ ei, int* __restrict__ deg, int* __restrict__ rank,
    int E, int EN)
{
    int e = blockIdx.x * 256 + threadIdx.x;
    if (e >= EN) return;
    int d = (e < E) ? ei[E + e] : (e - E);
    rank[e] = atomicAdd(&deg[d], 1);   // coalesced rank store; no downstream dep
}

// block scans 1024 elements (256 threads x 4)
__global__ __launch_bounds__(256) void scan1_k(
    const int* __restrict__ deg, int* __restrict__ partial,
    int* __restrict__ bsum, int n)
{
    __shared__ int lds[256];
    int t = threadIdx.x;
    int base = blockIdx.x * 1024 + t * 4;
    int v0 = (base + 0 < n) ? deg[base + 0] : 0;
    int v1 = (base + 1 < n) ? deg[base + 1] : 0;
    int v2 = (base + 2 < n) ? deg[base + 2] : 0;
    int v3 = (base + 3 < n) ? deg[base + 3] : 0;
    int s = v0 + v1 + v2 + v3;
    lds[t] = s;
    __syncthreads();
    for (int o = 1; o < 256; o <<= 1) {
        int x = (t >= o) ? lds[t - o] : 0;
        __syncthreads();
        lds[t] += x;
        __syncthreads();
    }
    int excl = lds[t] - s;
    if (t == 255) bsum[blockIdx.x] = lds[255];
    if (base + 0 < n) partial[base + 0] = excl;
    if (base + 1 < n) partial[base + 1] = excl + v0;
    if (base + 2 < n) partial[base + 2] = excl + v0 + v1;
    if (base + 3 < n) partial[base + 3] = excl + v0 + v1 + v2;
}

__global__ __launch_bounds__(256) void scan2_k(int* __restrict__ bsum, int nb)
{
    __shared__ int lds[256];
    int t = threadIdx.x;
    int base = t * 4;
    int v0 = (base + 0 < nb) ? bsum[base + 0] : 0;
    int v1 = (base + 1 < nb) ? bsum[base + 1] : 0;
    int v2 = (base + 2 < nb) ? bsum[base + 2] : 0;
    int v3 = (base + 3 < nb) ? bsum[base + 3] : 0;
    int s = v0 + v1 + v2 + v3;
    lds[t] = s;
    __syncthreads();
    for (int o = 1; o < 256; o <<= 1) {
        int x = (t >= o) ? lds[t - o] : 0;
        __syncthreads();
        lds[t] += x;
        __syncthreads();
    }
    int excl = lds[t] - s;
    if (base + 0 < nb) bsum[base + 0] = excl;
    if (base + 1 < nb) bsum[base + 1] = excl + v0;
    if (base + 2 < nb) bsum[base + 2] = excl + v0 + v1;
    if (base + 3 < nb) bsum[base + 3] = excl + v0 + v1 + v2;
}

__global__ __launch_bounds__(256) void scan3_k(
    const int* __restrict__ partial, const int* __restrict__ bsum,
    int* __restrict__ rowptr, int n, int EN)
{
    int i = blockIdx.x * 256 + threadIdx.x;
    if (i == 0) rowptr[n] = EN;
    if (i >= n) return;
    rowptr[i] = partial[i] + bsum[i >> 10];
}

// atomic-free scatter: col[rowptr[d] + rank[e]] = s
__global__ __launch_bounds__(256) void fill_k(
    const int* __restrict__ ei, const int* __restrict__ rank,
    const int* __restrict__ rowptr, int* __restrict__ col, int E, int EN)
{
    int e = blockIdx.x * 256 + threadIdx.x;
    if (e >= EN) return;
    int s, d;
    if (e < E) { s = ei[e]; d = ei[E + e]; } else { s = e - E; d = s; }
    col[rowptr[d] + rank[e]] = s;
}

// ============================================================
// h = act(X [+bias]) @ W ; asrc/adst in fp32; H stored as bf16x2
// ============================================================
__global__ __launch_bounds__(256) void gemm_attn(
    const float* __restrict__ X, const float* __restrict__ W,
    const float* __restrict__ av_s, const float* __restrict__ av_d,
    const float* __restrict__ bias, int relu_bias,
    unsigned* __restrict__ Hu, float* __restrict__ Asrc, float* __restrict__ Adst,
    int n)
{
    __shared__ float Ws[64 * 64];
    __shared__ float as_s[64], ad_s[64], b_s[64];
    int t = threadIdx.x;
    for (int i = t; i < 64 * 64; i += 256) Ws[i] = W[i];
    if (t < 64) { as_s[t] = av_s[t]; ad_s[t] = av_d[t]; b_s[t] = bias[t]; }
    __syncthreads();

    int row = blockIdx.x * 256 + t;
    if (row >= n) return;

    const float* xp = X + (size_t)row * 64;
    float xr[64];
    #pragma unroll
    for (int k = 0; k < 64; k += 4) {
        float4 v = *reinterpret_cast<const float4*>(xp + k);
        if (relu_bias) {
            v.x = fmaxf(v.x + b_s[k],     0.f);
            v.y = fmaxf(v.y + b_s[k + 1], 0.f);
            v.z = fmaxf(v.z + b_s[k + 2], 0.f);
            v.w = fmaxf(v.w + b_s[k + 3], 0.f);
        }
        xr[k] = v.x; xr[k + 1] = v.y; xr[k + 2] = v.z; xr[k + 3] = v.w;
    }

    float ss = 0.f, sd = 0.f;
    unsigned* hp = Hu + (size_t)row * 32;   // 32 uints = 64 bf16
    #pragma unroll 1
    for (int j = 0; j < 64; j += 4) {
        float a0 = 0.f, a1 = 0.f, a2 = 0.f, a3 = 0.f;
        #pragma unroll
        for (int k = 0; k < 64; k++) {
            float4 w = *reinterpret_cast<const float4*>(&Ws[k * 64 + j]);
            a0 += xr[k] * w.x; a1 += xr[k] * w.y;
            a2 += xr[k] * w.z; a3 += xr[k] * w.w;
        }
        uint2 o;
        o.x = f2bf(a0) | (f2bf(a1) << 16);   // low = feature j, high = j+1
        o.y = f2bf(a2) | (f2bf(a3) << 16);
        *reinterpret_cast<uint2*>(hp + (j >> 1)) = o;
        ss += a0 * as_s[j] + a1 * as_s[j + 1] + a2 * as_s[j + 2] + a3 * as_s[j + 3];
        sd += a0 * ad_s[j] + a1 * ad_s[j + 1] + a2 * ad_s[j + 2] + a3 * ad_s[j + 3];
    }
    Asrc[row] = ss;
    Adst[row] = sd;
}

// ============================================================
// pull aggregation: one wave per dst node.
// Phase A (deg<=64 fast path): lane = in-edge, register softmax.
// Phase B: half-waves — lanes 0..31 edge j, lanes 32..63 edge j+1;
//          each lane loads one bf16x2 (2 features). Cross-half
//          reduction via shfl_xor(32), coalesced float2 store.
// ============================================================
__global__ __launch_bounds__(256) void node_agg_k(
    const int* __restrict__ rowptr, const int* __restrict__ col,
    const float* __restrict__ Asrc, const float* __restrict__ Adst,
    const unsigned* __restrict__ Hu, float* __restrict__ agg, int n)
{
    __shared__ float lds_a[4][64];
    __shared__ int   lds_s[4][64];
    int wi   = threadIdx.x >> 6;
    int lane = threadIdx.x & 63;
    int w = blockIdx.x * 4 + wi;
    if (w >= n) return;

    int beg = rowptr[w];
    int end = rowptr[w + 1];
    int deg = end - beg;
    float adst = Adst[w];

    if (deg <= 64) {
        // ---- phase A: single gather, register softmax ----
        int   s = 0;
        float l = -3.4e38f;
        if (lane < deg) {
            s = col[beg + lane];
            float v = Asrc[s] + adst;
            l = v > 0.f ? v : NEG_SLOPE * v;
        }
        float m = l;
        #pragma unroll
        for (int o = 32; o; o >>= 1) m = fmaxf(m, __shfl_xor(m, o, 64));
        float ex = (lane < deg) ? __expf(l - m) : 0.f;
        float den = ex;
        #pragma unroll
        for (int o = 32; o; o >>= 1) den += __shfl_xor(den, o, 64);
        float alpha = ex / (den + 1e-16f);   // lanes >= deg carry alpha = 0

        // ---- phase B: 2 edges per iteration via half-waves ----
        int half = lane >> 5;      // 0: edge j, 1: edge j+1
        int fl   = lane & 31;      // feature pair index
        float a0 = 0.f, a1 = 0.f;
        for (int j = 0; j < deg; j += 2) {
            int jj = j + half;                    // <= deg <= 64-1 edge slot (alpha=0 pads)
            int   sj = __shfl(s,     jj, 64);
            float p  = __shfl(alpha, jj, 64);
            unsigned hv = Hu[(size_t)sj * 32 + fl];
            float hx = __uint_as_float(hv << 16);
            float hy = __uint_as_float(hv & 0xffff0000u);
            a0 += p * hx;
            a1 += p * hy;
        }
        a0 += __shfl_xor(a0, 32, 64);
        a1 += __shfl_xor(a1, 32, 64);
        if (half == 0) {
            float2 o; o.x = a0; o.y = a1;
            *reinterpret_cast<float2*>(agg + (size_t)w * 64 + 2 * fl) = o;
        }
        return;
    }

    // ---- generic path (deg > 64, rare): lane = feature ----
    float m = -3.4e38f;
    for (int i = beg + lane; i < end; i += 64) {
        float l = Asrc[col[i]] + adst;
        l = l > 0.f ? l : NEG_SLOPE * l;
        m = fmaxf(m, l);
    }
    #pragma unroll
    for (int o = 32; o; o >>= 1) m = fmaxf(m, __shfl_xor(m, o, 64));

    float den = 0.f;
    for (int i = beg + lane; i < end; i += 64) {
        float l = Asrc[col[i]] + adst;
        l = l > 0.f ? l : NEG_SLOPE * l;
        den += __expf(l - m);
    }
    #pragma unroll
    for (int o = 32; o; o >>= 1) den += __shfl_xor(den, o, 64);
    float inv = 1.f / (den + 1e-16f);

    float acc = 0.f;
    const unsigned short* Hs = (const unsigned short*)Hu;
    for (int cbeg = beg; cbeg < end; cbeg += 64) {
        int cnt = min(64, end - cbeg);
        int i = cbeg + lane;
        if (lane < cnt) {
            int s = col[i];
            float l = Asrc[s] + adst;
            l = l > 0.f ? l : NEG_SLOPE * l;
            lds_a[wi][lane] = __expf(l - m) * inv;
            lds_s[wi][lane] = s;
        }
        for (int j = 0; j < cnt; j++) {
            unsigned hv = Hs[(size_t)lds_s[wi][j] * 64 + lane];
            acc += lds_a[wi][j] * __uint_as_float(hv << 16);
        }
    }
    agg[(size_t)w * 64 + lane] = acc;
}

// ============================================================
// classifier: relu(agg + b2) @ Wc + bc -> log_softmax (C=2)
// ============================================================
__global__ __launch_bounds__(256) void classifier_k(
    const float* __restrict__ agg, const float* __restrict__ bias,
    const float* __restrict__ Wc, const float* __restrict__ bc,
    float* __restrict__ out, int n)
{
    __shared__ float Wcs[128], bs[64], bcs[2];
    int t = threadIdx.x;
    if (t < 128) Wcs[t] = Wc[t];
    if (t < 64) bs[t] = bias[t];
    if (t < 2) bcs[t] = bc[t];
    __syncthreads();

    int row = blockIdx.x * 256 + t;
    if (row >= n) return;
    const float* ap = agg + (size_t)row * 64;
    float z0 = bcs[0], z1 = bcs[1];
    #pragma unroll
    for (int k = 0; k < 64; k++) {
        float h = fmaxf(ap[k] + bs[k], 0.f);
        z0 += h * Wcs[2 * k];
        z1 += h * Wcs[2 * k + 1];
    }
    float m = fmaxf(z0, z1);
    float lse = m + logf(__expf(z0 - m) + __expf(z1 - m));
    out[(size_t)row * 2]     = z0 - lse;
    out[(size_t)row * 2 + 1] = z1 - lse;
}

extern "C" void kernel_launch(void* const* d_in, const int* in_sizes, int n_in,
                              void* d_out, int out_size, void* d_ws, size_t ws_size,
                              hipStream_t stream)
{
    const float* x   = (const float*)d_in[0];
    const int*   ei  = (const int*)d_in[1];
    const float* W1  = (const float*)d_in[2];
    const float* as1 = (const float*)d_in[3];
    const float* ad1 = (const float*)d_in[4];
    const float* b1  = (const float*)d_in[5];
    const float* W2  = (const float*)d_in[6];
    const float* as2 = (const float*)d_in[7];
    const float* ad2 = (const float*)d_in[8];
    const float* b2  = (const float*)d_in[9];
    const float* Wc  = (const float*)d_in[10];
    const float* bc  = (const float*)d_in[11];
    float* out = (float*)d_out;

    const int N  = in_sizes[0] / 64;   // 100000
    const int E  = in_sizes[1] / 2;    // 1200000
    const int EN = E + N;

    // workspace layout (4B elems), same footprint as before:
    // h[N*64] (only first N*32 uints used for bf16 H) | agg[N*64] | asrc[N] |
    // adst[N] | deg[N] | partial[N] | rowptr[N+1] | bsum[1024] | col[EN]
    // rank[EN] aliases agg (agg dead until first node_agg_k).
    float* h    = (float*)d_ws;
    float* agg  = h + (size_t)N * 64;
    float* asrc = agg + (size_t)N * 64;
    float* adst = asrc + N;
    int* deg     = (int*)(adst + N);
    int* partial = deg + N;
    int* rowptr  = partial + N;
    int* bsum    = rowptr + (N + 1);
    int* col     = bsum + 1024;
    int* rank    = (int*)agg;
    unsigned* Hu = (unsigned*)h;

    const int gN  = (N + 255) / 256;
    const int gE  = (EN + 255) / 256;
    const int gSc = (N + 1023) / 1024;
    const int gW  = (N + 3) / 4;

    // ---------------- CSR build (shared by both layers) ----------------
    hipMemsetAsync(deg, 0, (size_t)N * sizeof(int), stream);
    count_rank_k<<<gE, 256, 0, stream>>>(ei, deg, rank, E, EN);
    scan1_k<<<gSc, 256, 0, stream>>>(deg, partial, bsum, N);
    scan2_k<<<1, 256, 0, stream>>>(bsum, gSc);
    scan3_k<<<gN, 256, 0, stream>>>(partial, bsum, rowptr, N, EN);
    fill_k<<<gE, 256, 0, stream>>>(ei, rank, rowptr, col, E, EN);

    // ---------------- layer 1 ----------------
    gemm_attn<<<gN, 256, 0, stream>>>(x, W1, as1, ad1, b1, 0, Hu, asrc, adst, N);
    node_agg_k<<<gW, 256, 0, stream>>>(rowptr, col, asrc, adst, Hu, agg, N);

    // ---------------- layer 2 ----------------
    gemm_attn<<<gN, 256, 0, stream>>>(agg, W2, as2, ad2, b1, 1, Hu, asrc, adst, N);
    node_agg_k<<<gW, 256, 0, stream>>>(rowptr, col, asrc, adst, Hu, agg, N);

    // ---------------- classifier ----------------
    classifier_k<<<gN, 256, 0, stream>>>(agg, b2, Wc, bc, out, N);
}

// Round 5
// 313.993 us; speedup vs baseline: 1.1808x; 1.1808x over previous
//
#include <hip/hip_runtime.h>
#include <math.h>

#define NEG_SLOPE 0.2f

// fp32 -> bf16 round-to-nearest-even
__device__ __forceinline__ unsigned f2bf(float f) {
    unsigned u = __float_as_uint(f);
    return (u + 0x7fffu + ((u >> 16) & 1u)) >> 16;
}

// ============================================================
// CSR build: count+rank -> scan (3 kernels) -> atomic-free fill
// ============================================================

__global__ __launch_bounds__(256) void count_rank_k(
    const int* __restrict__ ei, int* __restrict__ deg, int* __restrict__ rank,
    int E, int EN)
{
    int e = blockIdx.x * 256 + threadIdx.x;
    if (e >= EN) return;
    int d = (e < E) ? ei[E + e] : (e - E);
    rank[e] = atomicAdd(&deg[d], 1);
}

__global__ __launch_bounds__(256) void scan1_k(
    const int* __restrict__ deg, int* __restrict__ partial,
    int* __restrict__ bsum, int n)
{
    __shared__ int lds[256];
    int t = threadIdx.x;
    int base = blockIdx.x * 1024 + t * 4;
    int v0 = (base + 0 < n) ? deg[base + 0] : 0;
    int v1 = (base + 1 < n) ? deg[base + 1] : 0;
    int v2 = (base + 2 < n) ? deg[base + 2] : 0;
    int v3 = (base + 3 < n) ? deg[base + 3] : 0;
    int s = v0 + v1 + v2 + v3;
    lds[t] = s;
    __syncthreads();
    for (int o = 1; o < 256; o <<= 1) {
        int x = (t >= o) ? lds[t - o] : 0;
        __syncthreads();
        lds[t] += x;
        __syncthreads();
    }
    int excl = lds[t] - s;
    if (t == 255) bsum[blockIdx.x] = lds[255];
    if (base + 0 < n) partial[base + 0] = excl;
    if (base + 1 < n) partial[base + 1] = excl + v0;
    if (base + 2 < n) partial[base + 2] = excl + v0 + v1;
    if (base + 3 < n) partial[base + 3] = excl + v0 + v1 + v2;
}

__global__ __launch_bounds__(256) void scan2_k(int* __restrict__ bsum, int nb)
{
    __shared__ int lds[256];
    int t = threadIdx.x;
    int base = t * 4;
    int v0 = (base + 0 < nb) ? bsum[base + 0] : 0;
    int v1 = (base + 1 < nb) ? bsum[base + 1] : 0;
    int v2 = (base + 2 < nb) ? bsum[base + 2] : 0;
    int v3 = (base + 3 < nb) ? bsum[base + 3] : 0;
    int s = v0 + v1 + v2 + v3;
    lds[t] = s;
    __syncthreads();
    for (int o = 1; o < 256; o <<= 1) {
        int x = (t >= o) ? lds[t - o] : 0;
        __syncthreads();
        lds[t] += x;
        __syncthreads();
    }
    int excl = lds[t] - s;
    if (base + 0 < nb) bsum[base + 0] = excl;
    if (base + 1 < nb) bsum[base + 1] = excl + v0;
    if (base + 2 < nb) bsum[base + 2] = excl + v0 + v1;
    if (base + 3 < nb) bsum[base + 3] = excl + v0 + v1 + v2;
}

__global__ __launch_bounds__(256) void scan3_k(
    const int* __restrict__ partial, const int* __restrict__ bsum,
    int* __restrict__ rowptr, int n, int EN)
{
    int i = blockIdx.x * 256 + threadIdx.x;
    if (i == 0) rowptr[n] = EN;
    if (i >= n) return;
    rowptr[i] = partial[i] + bsum[i >> 10];
}

__global__ __launch_bounds__(256) void fill_k(
    const int* __restrict__ ei, const int* __restrict__ rank,
    const int* __restrict__ rowptr, int* __restrict__ col, int E, int EN)
{
    int e = blockIdx.x * 256 + threadIdx.x;
    if (e >= EN) return;
    int s, d;
    if (e < E) { s = ei[e]; d = ei[E + e]; } else { s = e - E; d = s; }
    col[rowptr[d] + rank[e]] = s;
}

// ============================================================
// h = act(X [+bias]) @ W ; asrc/adst fp32; H stored as bf16x2
// ============================================================
__global__ __launch_bounds__(256) void gemm_attn(
    const float* __restrict__ X, const float* __restrict__ W,
    const float* __restrict__ av_s, const float* __restrict__ av_d,
    const float* __restrict__ bias, int relu_bias,
    unsigned* __restrict__ Hu, float* __restrict__ Asrc, float* __restrict__ Adst,
    int n)
{
    __shared__ float Ws[64 * 64];
    __shared__ float as_s[64], ad_s[64], b_s[64];
    int t = threadIdx.x;
    for (int i = t; i < 64 * 64; i += 256) Ws[i] = W[i];
    if (t < 64) { as_s[t] = av_s[t]; ad_s[t] = av_d[t]; b_s[t] = bias[t]; }
    __syncthreads();

    int row = blockIdx.x * 256 + t;
    if (row >= n) return;

    const float* xp = X + (size_t)row * 64;
    float xr[64];
    #pragma unroll
    for (int k = 0; k < 64; k += 4) {
        float4 v = *reinterpret_cast<const float4*>(xp + k);
        if (relu_bias) {
            v.x = fmaxf(v.x + b_s[k],     0.f);
            v.y = fmaxf(v.y + b_s[k + 1], 0.f);
            v.z = fmaxf(v.z + b_s[k + 2], 0.f);
            v.w = fmaxf(v.w + b_s[k + 3], 0.f);
        }
        xr[k] = v.x; xr[k + 1] = v.y; xr[k + 2] = v.z; xr[k + 3] = v.w;
    }

    float ss = 0.f, sd = 0.f;
    unsigned* hp = Hu + (size_t)row * 32;
    #pragma unroll 1
    for (int j = 0; j < 64; j += 4) {
        float a0 = 0.f, a1 = 0.f, a2 = 0.f, a3 = 0.f;
        #pragma unroll
        for (int k = 0; k < 64; k++) {
            float4 w = *reinterpret_cast<const float4*>(&Ws[k * 64 + j]);
            a0 += xr[k] * w.x; a1 += xr[k] * w.y;
            a2 += xr[k] * w.z; a3 += xr[k] * w.w;
        }
        uint2 o;
        o.x = f2bf(a0) | (f2bf(a1) << 16);
        o.y = f2bf(a2) | (f2bf(a3) << 16);
        *reinterpret_cast<uint2*>(hp + (j >> 1)) = o;
        ss += a0 * as_s[j] + a1 * as_s[j + 1] + a2 * as_s[j + 2] + a3 * as_s[j + 3];
        sd += a0 * ad_s[j] + a1 * ad_s[j + 1] + a2 * ad_s[j + 2] + a3 * ad_s[j + 3];
    }
    Asrc[row] = ss;
    Adst[row] = sd;
}

// ============================================================
// pull aggregation: TWO nodes per wave.
// Phase A: lanes 0-31 = node w2's in-edges, lanes 32-63 = node
//   w2+1's (deg<=32 fast path); softmax via 5-step half-wave shfl.
// Phase B (per node): quarter-waves — one dwordx2 (4 bf16) per
//   lane covers 4 edge-rows per load instruction; 16 edges per
//   unrolled iteration = 4 independent loads in flight.
// ============================================================
__global__ __launch_bounds__(256) void node_agg_k(
    const int* __restrict__ rowptr, const int* __restrict__ col,
    const float* __restrict__ Asrc, const float* __restrict__ Adst,
    const unsigned* __restrict__ Hu, float* __restrict__ agg, int n)
{
    __shared__ float lds_a[4][64];
    __shared__ int   lds_s[4][64];
    int wi   = threadIdx.x >> 6;
    int lane = threadIdx.x & 63;
    int half = lane >> 5, hl = lane & 31;
    int w2 = (blockIdx.x * 4 + wi) * 2;
    if (w2 >= n) return;
    int w  = w2 + half;
    int wc = (w < n) ? w : (n - 1);

    int beg = rowptr[wc];
    int deg = rowptr[wc + 1] - beg;
    bool fast = (deg <= 32);

    // ---- phase A: per-half register softmax ----
    int s = 0; float l = -3.4e38f;
    if (fast && hl < deg) {
        s = col[beg + hl];
        float v = Asrc[s] + Adst[wc];
        l = v > 0.f ? v : NEG_SLOPE * v;
    }
    float m = l;
    #pragma unroll
    for (int o = 16; o; o >>= 1) m = fmaxf(m, __shfl_xor(m, o, 64));
    float ex = (fast && hl < deg) ? __expf(l - m) : 0.f;
    float den = ex;
    #pragma unroll
    for (int o = 16; o; o >>= 1) den += __shfl_xor(den, o, 64);
    float alpha = ex / (den + 1e-16f);   // 0 on invalid/padded lanes

    const uint2* Hu2 = (const uint2*)Hu;
    int q = lane >> 4, fl = lane & 15;

    // ---- phase B: the pair's nodes, sequentially, full wave each ----
    for (int h = 0; h < 2; h++) {
        int wn = w2 + h;
        if (wn >= n) break;
        int dg = __shfl(deg, h * 32, 64);

        if (dg <= 32) {
            int degP = (dg + 15) & ~15;          // 16 or 32
            float ax = 0.f, ay = 0.f, az = 0.f, aw = 0.f;
            for (int j = 0; j < degP; j += 16) {
                #pragma unroll
                for (int i = 0; i < 4; i++) {
                    int e   = j + 4 * i + q;     // this quarter's edge
                    int idx = h * 32 + e;        // lane holding it
                    int   se = __shfl(s,     idx, 64);
                    float pe = __shfl(alpha, idx, 64);
                    uint2 hv = Hu2[(size_t)se * 16 + fl];
                    ax += pe * __uint_as_float(hv.x << 16);
                    ay += pe * __uint_as_float(hv.x & 0xffff0000u);
                    az += pe * __uint_as_float(hv.y << 16);
                    aw += pe * __uint_as_float(hv.y & 0xffff0000u);
                }
            }
            // cross-quarter reduction
            ax += __shfl_xor(ax, 16, 64); ax += __shfl_xor(ax, 32, 64);
            ay += __shfl_xor(ay, 16, 64); ay += __shfl_xor(ay, 32, 64);
            az += __shfl_xor(az, 16, 64); az += __shfl_xor(az, 32, 64);
            aw += __shfl_xor(aw, 16, 64); aw += __shfl_xor(aw, 32, 64);
            if (lane < 16) {
                float4 o; o.x = ax; o.y = ay; o.z = az; o.w = aw;
                *reinterpret_cast<float4*>(agg + (size_t)wn * 64 + 4 * fl) = o;
            }
        } else {
            // ---- generic fallback (deg > 32): full wave, lane = feature ----
            int begN = __shfl(beg, h * 32, 64);
            int endN = begN + dg;
            float adstN = Adst[wn];
            float mm = -3.4e38f;
            for (int i = begN + lane; i < endN; i += 64) {
                float v = Asrc[col[i]] + adstN;
                v = v > 0.f ? v : NEG_SLOPE * v;
                mm = fmaxf(mm, v);
            }
            #pragma unroll
            for (int o = 32; o; o >>= 1) mm = fmaxf(mm, __shfl_xor(mm, o, 64));
            float dd = 0.f;
            for (int i = begN + lane; i < endN; i += 64) {
                float v = Asrc[col[i]] + adstN;
                v = v > 0.f ? v : NEG_SLOPE * v;
                dd += __expf(v - mm);
            }
            #pragma unroll
            for (int o = 32; o; o >>= 1) dd += __shfl_xor(dd, o, 64);
            float inv = 1.f / (dd + 1e-16f);

            const unsigned short* Hs = (const unsigned short*)Hu;
            float acc = 0.f;
            for (int cbeg = begN; cbeg < endN; cbeg += 64) {
                int cnt = min(64, endN - cbeg);
                if (lane < cnt) {
                    int ss2 = col[cbeg + lane];
                    float v = Asrc[ss2] + adstN;
                    v = v > 0.f ? v : NEG_SLOPE * v;
                    lds_a[wi][lane] = __expf(v - mm) * inv;
                    lds_s[wi][lane] = ss2;
                }
                for (int j2 = 0; j2 < cnt; j2++) {
                    unsigned hv = (unsigned)Hs[(size_t)lds_s[wi][j2] * 64 + lane];
                    acc += lds_a[wi][j2] * __uint_as_float(hv << 16);
                }
            }
            agg[(size_t)wn * 64 + lane] = acc;
        }
    }
}

// ============================================================
// classifier: relu(agg + b2) @ Wc + bc -> log_softmax (C=2)
// ============================================================
__global__ __launch_bounds__(256) void classifier_k(
    const float* __restrict__ agg, const float* __restrict__ bias,
    const float* __restrict__ Wc, const float* __restrict__ bc,
    float* __restrict__ out, int n)
{
    __shared__ float Wcs[128], bs[64], bcs[2];
    int t = threadIdx.x;
    if (t < 128) Wcs[t] = Wc[t];
    if (t < 64) bs[t] = bias[t];
    if (t < 2) bcs[t] = bc[t];
    __syncthreads();

    int row = blockIdx.x * 256 + t;
    if (row >= n) return;
    const float* ap = agg + (size_t)row * 64;
    float z0 = bcs[0], z1 = bcs[1];
    #pragma unroll
    for (int k = 0; k < 64; k++) {
        float h = fmaxf(ap[k] + bs[k], 0.f);
        z0 += h * Wcs[2 * k];
        z1 += h * Wcs[2 * k + 1];
    }
    float m = fmaxf(z0, z1);
    float lse = m + logf(__expf(z0 - m) + __expf(z1 - m));
    out[(size_t)row * 2]     = z0 - lse;
    out[(size_t)row * 2 + 1] = z1 - lse;
}

extern "C" void kernel_launch(void* const* d_in, const int* in_sizes, int n_in,
                              void* d_out, int out_size, void* d_ws, size_t ws_size,
                              hipStream_t stream)
{
    const float* x   = (const float*)d_in[0];
    const int*   ei  = (const int*)d_in[1];
    const float* W1  = (const float*)d_in[2];
    const float* as1 = (const float*)d_in[3];
    const float* ad1 = (const float*)d_in[4];
    const float* b1  = (const float*)d_in[5];
    const float* W2  = (const float*)d_in[6];
    const float* as2 = (const float*)d_in[7];
    const float* ad2 = (const float*)d_in[8];
    const float* b2  = (const float*)d_in[9];
    const float* Wc  = (const float*)d_in[10];
    const float* bc  = (const float*)d_in[11];
    float* out = (float*)d_out;

    const int N  = in_sizes[0] / 64;   // 100000
    const int E  = in_sizes[1] / 2;    // 1200000
    const int EN = E + N;

    // workspace: h[N*64] (bf16 H in first N*32 uints) | agg[N*64] | asrc[N] |
    // adst[N] | deg[N] | partial[N] | rowptr[N+1] | bsum[1024] | col[EN]
    // rank[EN] aliases agg.
    float* h    = (float*)d_ws;
    float* agg  = h + (size_t)N * 64;
    float* asrc = agg + (size_t)N * 64;
    float* adst = asrc + N;
    int* deg     = (int*)(adst + N);
    int* partial = deg + N;
    int* rowptr  = partial + N;
    int* bsum    = rowptr + (N + 1);
    int* col     = bsum + 1024;
    int* rank    = (int*)agg;
    unsigned* Hu = (unsigned*)h;

    const int gN  = (N + 255) / 256;
    const int gE  = (EN + 255) / 256;
    const int gSc = (N + 1023) / 1024;
    const int gW  = (N + 7) / 8;       // 4 waves/block x 2 nodes/wave

    // ---------------- CSR build ----------------
    hipMemsetAsync(deg, 0, (size_t)N * sizeof(int), stream);
    count_rank_k<<<gE, 256, 0, stream>>>(ei, deg, rank, E, EN);
    scan1_k<<<gSc, 256, 0, stream>>>(deg, partial, bsum, N);
    scan2_k<<<1, 256, 0, stream>>>(bsum, gSc);
    scan3_k<<<gN, 256, 0, stream>>>(partial, bsum, rowptr, N, EN);
    fill_k<<<gE, 256, 0, stream>>>(ei, rank, rowptr, col, E, EN);

    // ---------------- layer 1 ----------------
    gemm_attn<<<gN, 256, 0, stream>>>(x, W1, as1, ad1, b1, 0, Hu, asrc, adst, N);
    node_agg_k<<<gW, 256, 0, stream>>>(rowptr, col, asrc, adst, Hu, agg, N);

    // ---------------- layer 2 ----------------
    gemm_attn<<<gN, 256, 0, stream>>>(agg, W2, as2, ad2, b1, 1, Hu, asrc, adst, N);
    node_agg_k<<<gW, 256, 0, stream>>>(rowptr, col, asrc, adst, Hu, agg, N);

    // ---------------- classifier ----------------
    classifier_k<<<gN, 256, 0, stream>>>(agg, b2, Wc, bc, out, N);
}

// Round 6
// 287.378 us; speedup vs baseline: 1.2901x; 1.0926x over previous
//
#include <hip/hip_runtime.h>
#include <math.h>

#define NEG_SLOPE 0.2f

// fp32 -> bf16 round-to-nearest-even
__device__ __forceinline__ unsigned f2bf(float f) {
    unsigned u = __float_as_uint(f);
    return (u + 0x7fffu + ((u >> 16) & 1u)) >> 16;
}

// ============================================================
// FUSED: layer-1 GEMM (blocks [0,gemmBlocks)) + count_rank
// (blocks [gemmBlocks, ...)). The atomic histogram is latency-
// bound (VALU ~1%) and hides behind the VALU-bound GEMM.
// ============================================================
__global__ __launch_bounds__(256) void gemm1_count_k(
    const float* __restrict__ X, const float* __restrict__ W,
    const float* __restrict__ av_s, const float* __restrict__ av_d,
    unsigned* __restrict__ Hu, float* __restrict__ Asrc, float* __restrict__ Adst,
    int n,
    const int* __restrict__ ei, int* __restrict__ deg, int* __restrict__ rank,
    int E, int EN, int gemmBlocks)
{
    __shared__ float Ws[64 * 64];
    __shared__ float as_s[64], ad_s[64];
    int t = threadIdx.x;

    if (blockIdx.x >= gemmBlocks) {
        // ---- count_rank path ----
        int e = (blockIdx.x - gemmBlocks) * 256 + t;
        if (e >= EN) return;
        int d = (e < E) ? ei[E + e] : (e - E);
        rank[e] = atomicAdd(&deg[d], 1);
        return;
    }

    // ---- GEMM path (relu_bias = 0) ----
    for (int i = t; i < 64 * 64; i += 256) Ws[i] = W[i];
    if (t < 64) { as_s[t] = av_s[t]; ad_s[t] = av_d[t]; }
    __syncthreads();

    int row = blockIdx.x * 256 + t;
    if (row >= n) return;

    const float* xp = X + (size_t)row * 64;
    float xr[64];
    #pragma unroll
    for (int k = 0; k < 64; k += 4) {
        float4 v = *reinterpret_cast<const float4*>(xp + k);
        xr[k] = v.x; xr[k + 1] = v.y; xr[k + 2] = v.z; xr[k + 3] = v.w;
    }

    float ss = 0.f, sd = 0.f;
    unsigned* hp = Hu + (size_t)row * 32;
    #pragma unroll 1
    for (int j = 0; j < 64; j += 4) {
        float a0 = 0.f, a1 = 0.f, a2 = 0.f, a3 = 0.f;
        #pragma unroll
        for (int k = 0; k < 64; k++) {
            float4 w = *reinterpret_cast<const float4*>(&Ws[k * 64 + j]);
            a0 += xr[k] * w.x; a1 += xr[k] * w.y;
            a2 += xr[k] * w.z; a3 += xr[k] * w.w;
        }
        uint2 o;
        o.x = f2bf(a0) | (f2bf(a1) << 16);
        o.y = f2bf(a2) | (f2bf(a3) << 16);
        *reinterpret_cast<uint2*>(hp + (j >> 1)) = o;
        ss += a0 * as_s[j] + a1 * as_s[j + 1] + a2 * as_s[j + 2] + a3 * as_s[j + 3];
        sd += a0 * ad_s[j] + a1 * ad_s[j + 1] + a2 * ad_s[j + 2] + a3 * ad_s[j + 3];
    }
    Asrc[row] = ss;
    Adst[row] = sd;
}

// ============================================================
// scan1: per-1024-block scan of degrees
// ============================================================
__global__ __launch_bounds__(256) void scan1_k(
    const int* __restrict__ deg, int* __restrict__ partial,
    int* __restrict__ bsum, int n)
{
    __shared__ int lds[256];
    int t = threadIdx.x;
    int base = blockIdx.x * 1024 + t * 4;
    int v0 = (base + 0 < n) ? deg[base + 0] : 0;
    int v1 = (base + 1 < n) ? deg[base + 1] : 0;
    int v2 = (base + 2 < n) ? deg[base + 2] : 0;
    int v3 = (base + 3 < n) ? deg[base + 3] : 0;
    int s = v0 + v1 + v2 + v3;
    lds[t] = s;
    __syncthreads();
    for (int o = 1; o < 256; o <<= 1) {
        int x = (t >= o) ? lds[t - o] : 0;
        __syncthreads();
        lds[t] += x;
        __syncthreads();
    }
    int excl = lds[t] - s;
    if (t == 255) bsum[blockIdx.x] = lds[255];
    if (base + 0 < n) partial[base + 0] = excl;
    if (base + 1 < n) partial[base + 1] = excl + v0;
    if (base + 2 < n) partial[base + 2] = excl + v0 + v1;
    if (base + 3 < n) partial[base + 3] = excl + v0 + v1 + v2;
}

// scan3: each block scans the (<=256) block sums itself, then
// emits rowptr. Replaces the old scan2+scan3 pair.
__global__ __launch_bounds__(256) void scan3_k(
    const int* __restrict__ partial, const int* __restrict__ bsum,
    int* __restrict__ rowptr, int n, int EN, int nb)
{
    __shared__ int lds[256];
    int t = threadIdx.x;
    lds[t] = (t < nb) ? bsum[t] : 0;
    __syncthreads();
    for (int o = 1; o < 256; o <<= 1) {
        int x = (t >= o) ? lds[t - o] : 0;
        __syncthreads();
        lds[t] += x;
        __syncthreads();
    }
    int i = blockIdx.x * 256 + t;
    if (i == 0) rowptr[n] = EN;
    if (i >= n) return;
    int b = i >> 10;
    int pre = (b == 0) ? 0 : lds[b - 1];
    rowptr[i] = partial[i] + pre;
}

// atomic-free scatter: col[rowptr[d] + rank[e]] = s
__global__ __launch_bounds__(256) void fill_k(
    const int* __restrict__ ei, const int* __restrict__ rank,
    const int* __restrict__ rowptr, int* __restrict__ col, int E, int EN)
{
    int e = blockIdx.x * 256 + threadIdx.x;
    if (e >= EN) return;
    int s, d;
    if (e < E) { s = ei[e]; d = ei[E + e]; } else { s = e - E; d = s; }
    col[rowptr[d] + rank[e]] = s;
}

// ============================================================
// layer-2 GEMM: h = relu(X + bias) @ W ; H bf16; asrc/adst fp32
// ============================================================
__global__ __launch_bounds__(256) void gemm_attn(
    const float* __restrict__ X, const float* __restrict__ W,
    const float* __restrict__ av_s, const float* __restrict__ av_d,
    const float* __restrict__ bias,
    unsigned* __restrict__ Hu, float* __restrict__ Asrc, float* __restrict__ Adst,
    int n)
{
    __shared__ float Ws[64 * 64];
    __shared__ float as_s[64], ad_s[64], b_s[64];
    int t = threadIdx.x;
    for (int i = t; i < 64 * 64; i += 256) Ws[i] = W[i];
    if (t < 64) { as_s[t] = av_s[t]; ad_s[t] = av_d[t]; b_s[t] = bias[t]; }
    __syncthreads();

    int row = blockIdx.x * 256 + t;
    if (row >= n) return;

    const float* xp = X + (size_t)row * 64;
    float xr[64];
    #pragma unroll
    for (int k = 0; k < 64; k += 4) {
        float4 v = *reinterpret_cast<const float4*>(xp + k);
        v.x = fmaxf(v.x + b_s[k],     0.f);
        v.y = fmaxf(v.y + b_s[k + 1], 0.f);
        v.z = fmaxf(v.z + b_s[k + 2], 0.f);
        v.w = fmaxf(v.w + b_s[k + 3], 0.f);
        xr[k] = v.x; xr[k + 1] = v.y; xr[k + 2] = v.z; xr[k + 3] = v.w;
    }

    float ss = 0.f, sd = 0.f;
    unsigned* hp = Hu + (size_t)row * 32;
    #pragma unroll 1
    for (int j = 0; j < 64; j += 4) {
        float a0 = 0.f, a1 = 0.f, a2 = 0.f, a3 = 0.f;
        #pragma unroll
        for (int k = 0; k < 64; k++) {
            float4 w = *reinterpret_cast<const float4*>(&Ws[k * 64 + j]);
            a0 += xr[k] * w.x; a1 += xr[k] * w.y;
            a2 += xr[k] * w.z; a3 += xr[k] * w.w;
        }
        uint2 o;
        o.x = f2bf(a0) | (f2bf(a1) << 16);
        o.y = f2bf(a2) | (f2bf(a3) << 16);
        *reinterpret_cast<uint2*>(hp + (j >> 1)) = o;
        ss += a0 * as_s[j] + a1 * as_s[j + 1] + a2 * as_s[j + 2] + a3 * as_s[j + 3];
        sd += a0 * ad_s[j] + a1 * ad_s[j + 1] + a2 * ad_s[j + 2] + a3 * ad_s[j + 3];
    }
    Asrc[row] = ss;
    Adst[row] = sd;
}

// ============================================================
// pull aggregation, two nodes per wave; optional fused
// classifier epilogue (layer 2): out = log_softmax(relu(row +
// b)@Wc + bc) computed in-register, no agg write.
// ============================================================
__global__ __launch_bounds__(256) void node_agg_k(
    const int* __restrict__ rowptr, const int* __restrict__ col,
    const float* __restrict__ Asrc, const float* __restrict__ Adst,
    const unsigned* __restrict__ Hu, float* __restrict__ agg, int n,
    const float* __restrict__ cls_b, const float* __restrict__ Wc,
    const float* __restrict__ bc, float* __restrict__ out, int do_cls)
{
    __shared__ float lds_a[4][64];
    __shared__ int   lds_s[4][64];
    int wi   = threadIdx.x >> 6;
    int lane = threadIdx.x & 63;
    int half = lane >> 5, hl = lane & 31;
    int w2 = (blockIdx.x * 4 + wi) * 2;
    if (w2 >= n) return;
    int w  = w2 + half;
    int wc = (w < n) ? w : (n - 1);

    int beg = rowptr[wc];
    int deg = rowptr[wc + 1] - beg;
    bool fast = (deg <= 32);

    // ---- phase A: per-half register softmax ----
    int s = 0; float l = -3.4e38f;
    if (fast && hl < deg) {
        s = col[beg + hl];
        float v = Asrc[s] + Adst[wc];
        l = v > 0.f ? v : NEG_SLOPE * v;
    }
    float m = l;
    #pragma unroll
    for (int o = 16; o; o >>= 1) m = fmaxf(m, __shfl_xor(m, o, 64));
    float ex = (fast && hl < deg) ? __expf(l - m) : 0.f;
    float den = ex;
    #pragma unroll
    for (int o = 16; o; o >>= 1) den += __shfl_xor(den, o, 64);
    float alpha = ex / (den + 1e-16f);   // 0 on invalid/padded lanes

    const uint2* Hu2 = (const uint2*)Hu;
    int q = lane >> 4, fl = lane & 15;

    for (int h = 0; h < 2; h++) {
        int wn = w2 + h;
        if (wn >= n) break;
        int dg = __shfl(deg, h * 32, 64);

        if (dg <= 32) {
            int degP = (dg + 15) & ~15;          // 16 or 32
            float ax = 0.f, ay = 0.f, az = 0.f, aw = 0.f;
            for (int j = 0; j < degP; j += 16) {
                #pragma unroll
                for (int i = 0; i < 4; i++) {
                    int e   = j + 4 * i + q;
                    int idx = h * 32 + e;
                    int   se = __shfl(s,     idx, 64);
                    float pe = __shfl(alpha, idx, 64);
                    uint2 hv = Hu2[(size_t)se * 16 + fl];
                    ax += pe * __uint_as_float(hv.x << 16);
                    ay += pe * __uint_as_float(hv.x & 0xffff0000u);
                    az += pe * __uint_as_float(hv.y << 16);
                    aw += pe * __uint_as_float(hv.y & 0xffff0000u);
                }
            }
            // cross-quarter reduction: afterwards ALL lanes hold the
            // final chunk for feature group fl = lane & 15
            ax += __shfl_xor(ax, 16, 64); ax += __shfl_xor(ax, 32, 64);
            ay += __shfl_xor(ay, 16, 64); ay += __shfl_xor(ay, 32, 64);
            az += __shfl_xor(az, 16, 64); az += __shfl_xor(az, 32, 64);
            aw += __shfl_xor(aw, 16, 64); aw += __shfl_xor(aw, 32, 64);
            if (do_cls) {
                float4 bb = *reinterpret_cast<const float4*>(cls_b + 4 * fl);
                float h0 = fmaxf(ax + bb.x, 0.f);
                float h1 = fmaxf(ay + bb.y, 0.f);
                float h2 = fmaxf(az + bb.z, 0.f);
                float h3 = fmaxf(aw + bb.w, 0.f);
                float4 wA = *reinterpret_cast<const float4*>(Wc + 8 * fl);
                float4 wB = *reinterpret_cast<const float4*>(Wc + 8 * fl + 4);
                float z0 = h0 * wA.x + h1 * wA.z + h2 * wB.x + h3 * wB.z;
                float z1 = h0 * wA.y + h1 * wA.w + h2 * wB.y + h3 * wB.w;
                #pragma unroll
                for (int o = 1; o < 16; o <<= 1) {
                    z0 += __shfl_xor(z0, o, 64);
                    z1 += __shfl_xor(z1, o, 64);
                }
                if (lane == 0) {
                    z0 += bc[0]; z1 += bc[1];
                    float mm = fmaxf(z0, z1);
                    float lse = mm + logf(__expf(z0 - mm) + __expf(z1 - mm));
                    out[(size_t)wn * 2]     = z0 - lse;
                    out[(size_t)wn * 2 + 1] = z1 - lse;
                }
            } else if (lane < 16) {
                float4 o; o.x = ax; o.y = ay; o.z = az; o.w = aw;
                *reinterpret_cast<float4*>(agg + (size_t)wn * 64 + 4 * fl) = o;
            }
        } else {
            // ---- generic fallback (deg > 32): full wave, lane = feature ----
            int begN = __shfl(beg, h * 32, 64);
            int endN = begN + dg;
            float adstN = Adst[wn];
            float mm = -3.4e38f;
            for (int i = begN + lane; i < endN; i += 64) {
                float v = Asrc[col[i]] + adstN;
                v = v > 0.f ? v : NEG_SLOPE * v;
                mm = fmaxf(mm, v);
            }
            #pragma unroll
            for (int o = 32; o; o >>= 1) mm = fmaxf(mm, __shfl_xor(mm, o, 64));
            float dd = 0.f;
            for (int i = begN + lane; i < endN; i += 64) {
                float v = Asrc[col[i]] + adstN;
                v = v > 0.f ? v : NEG_SLOPE * v;
                dd += __expf(v - mm);
            }
            #pragma unroll
            for (int o = 32; o; o >>= 1) dd += __shfl_xor(dd, o, 64);
            float inv = 1.f / (dd + 1e-16f);

            const unsigned short* Hs = (const unsigned short*)Hu;
            float acc = 0.f;
            for (int cbeg = begN; cbeg < endN; cbeg += 64) {
                int cnt = min(64, endN - cbeg);
                if (lane < cnt) {
                    int ss2 = col[cbeg + lane];
                    float v = Asrc[ss2] + adstN;
                    v = v > 0.f ? v : NEG_SLOPE * v;
                    lds_a[wi][lane] = __expf(v - mm) * inv;
                    lds_s[wi][lane] = ss2;
                }
                for (int j2 = 0; j2 < cnt; j2++) {
                    unsigned hv = (unsigned)Hs[(size_t)lds_s[wi][j2] * 64 + lane];
                    acc += lds_a[wi][j2] * __uint_as_float(hv << 16);
                }
            }
            if (do_cls) {
                float hh = fmaxf(acc + cls_b[lane], 0.f);
                float z0 = hh * Wc[2 * lane];
                float z1 = hh * Wc[2 * lane + 1];
                #pragma unroll
                for (int o = 1; o < 64; o <<= 1) {
                    z0 += __shfl_xor(z0, o, 64);
                    z1 += __shfl_xor(z1, o, 64);
                }
                if (lane == 0) {
                    z0 += bc[0]; z1 += bc[1];
                    float mm2 = fmaxf(z0, z1);
                    float lse = mm2 + logf(__expf(z0 - mm2) + __expf(z1 - mm2));
                    out[(size_t)wn * 2]     = z0 - lse;
                    out[(size_t)wn * 2 + 1] = z1 - lse;
                }
            } else {
                agg[(size_t)wn * 64 + lane] = acc;
            }
        }
    }
}

extern "C" void kernel_launch(void* const* d_in, const int* in_sizes, int n_in,
                              void* d_out, int out_size, void* d_ws, size_t ws_size,
                              hipStream_t stream)
{
    const float* x   = (const float*)d_in[0];
    const int*   ei  = (const int*)d_in[1];
    const float* W1  = (const float*)d_in[2];
    const float* as1 = (const float*)d_in[3];
    const float* ad1 = (const float*)d_in[4];
    const float* b1  = (const float*)d_in[5];
    const float* W2  = (const float*)d_in[6];
    const float* as2 = (const float*)d_in[7];
    const float* ad2 = (const float*)d_in[8];
    const float* b2  = (const float*)d_in[9];
    const float* Wc  = (const float*)d_in[10];
    const float* bc  = (const float*)d_in[11];
    float* out = (float*)d_out;

    const int N  = in_sizes[0] / 64;   // 100000
    const int E  = in_sizes[1] / 2;    // 1200000
    const int EN = E + N;

    // workspace: h[N*64] (bf16 H in first N*32 uints) | agg[N*64] | asrc[N] |
    // adst[N] | deg[N] | partial[N] | rowptr[N+1] | bsum[1024] | col[EN]
    // rank[EN] aliases agg (dead by first node_agg).
    float* h    = (float*)d_ws;
    float* agg  = h + (size_t)N * 64;
    float* asrc = agg + (size_t)N * 64;
    float* adst = asrc + N;
    int* deg     = (int*)(adst + N);
    int* partial = deg + N;
    int* rowptr  = partial + N;
    int* bsum    = rowptr + (N + 1);
    int* col     = bsum + 1024;
    int* rank    = (int*)agg;
    unsigned* Hu = (unsigned*)h;

    const int gN  = (N + 255) / 256;
    const int gE  = (EN + 255) / 256;
    const int gSc = (N + 1023) / 1024;   // <= 256 (required by scan3)
    const int gW  = (N + 7) / 8;

    // ---------------- CSR build + layer-1 GEMM (fused) ----------------
    hipMemsetAsync(deg, 0, (size_t)N * sizeof(int), stream);
    gemm1_count_k<<<gN + gE, 256, 0, stream>>>(
        x, W1, as1, ad1, Hu, asrc, adst, N, ei, deg, rank, E, EN, gN);
    scan1_k<<<gSc, 256, 0, stream>>>(deg, partial, bsum, N);
    scan3_k<<<gN, 256, 0, stream>>>(partial, bsum, rowptr, N, EN, gSc);
    fill_k<<<gE, 256, 0, stream>>>(ei, rank, rowptr, col, E, EN);

    // ---------------- layer 1 aggregation ----------------
    node_agg_k<<<gW, 256, 0, stream>>>(rowptr, col, asrc, adst, Hu, agg, N,
                                       nullptr, nullptr, nullptr, nullptr, 0);

    // ---------------- layer 2 (bias+relu fused into GEMM load) ----------------
    gemm_attn<<<gN, 256, 0, stream>>>(agg, W2, as2, ad2, b1, Hu, asrc, adst, N);

    // ---------------- layer 2 aggregation + classifier epilogue ----------------
    node_agg_k<<<gW, 256, 0, stream>>>(rowptr, col, asrc, adst, Hu, nullptr, N,
                                       b2, Wc, bc, out, 1);
}